// Round 10
// baseline (274.307 us; speedup 1.0000x reference)
//
#include <hip/hip_runtime.h>

#define N_    50000
#define E_    320000
#define R_    16
#define B_    8
#define IN_   256
#define OUT_  256
#define EPR_  (E_ / R_)        // 20000 edges per relation
#define MBLK_ 157              // ceil(EPR_/128)
#define NBLK_ 391              // ceil(N_/128) (also selfloop tiles)
#define NB_   391              // src buckets per relation (128 nodes each)
#define KTOT_ (R_ * NB_)       // 6256 bucket keys
#define SCN_  (N_ + KTOT_)     // 56256 combined scan length
#define SCB_  220              // ceil(SCN_/256)
#define TIL_  (R_ * MBLK_ + NBLK_)  // 2903 edge tiles (incl. selfloop)

typedef float  f32x16 __attribute__((ext_vector_type(16)));
typedef __bf16 bf16x8 __attribute__((ext_vector_type(8)));

static __device__ __forceinline__ short f2bf(float f) {
  unsigned u = __float_as_uint(f);
  u = (u + 0x7FFFu + ((u >> 16) & 1u)) >> 16;   // RNE
  return (short)u;
}
static __device__ __forceinline__ float bf2f(unsigned short s) {
  return __uint_as_float(((unsigned)s) << 16);
}

// async global->LDS, 16B per lane; LDS dest = wave-uniform base + lane*16
static __device__ __forceinline__ void gl_lds16(const short* g, short* l) {
  __builtin_amdgcn_global_load_lds(
      (const __attribute__((address_space(1))) void*)g,
      (__attribute__((address_space(3))) void*)l, 16, 0, 0);
}

// ---------------------------------------------------------------------------
// prep: w_relT slots 0..15 = basis-composed relation weights (bf16, [o][i]);
//       slot 16 = transposed loop_weight. feat -> bf16 (RNE). zero counters.
// ---------------------------------------------------------------------------
__global__ void prep_kernel(const float* __restrict__ feat, const float* __restrict__ weight,
                            const float* __restrict__ w_comp, const float* __restrict__ loop_w,
                            short* __restrict__ w_relT, short* __restrict__ feat_bf,
                            int* __restrict__ counts, int* __restrict__ counts2) {
  int gid = blockIdx.x * blockDim.x + threadIdx.x;
  int gsz = gridDim.x * blockDim.x;
  for (int idx = gid; idx < R_ * OUT_ * IN_; idx += gsz) {
    int r = idx >> 16, i = (idx >> 8) & 255, o = idx & 255;  // o fastest: coalesced weight reads
    float s = 0.f;
#pragma unroll
    for (int b = 0; b < B_; ++b)
      s += w_comp[r * B_ + b] * weight[(b * IN_ + i) * OUT_ + o];
    w_relT[(r * OUT_ + o) * IN_ + i] = f2bf(s);
  }
  for (int idx = gid; idx < OUT_ * IN_; idx += gsz) {
    int i = idx >> 8, o = idx & 255;
    w_relT[((R_ * OUT_) + o) * IN_ + i] = f2bf(loop_w[i * OUT_ + o]);   // slot 16
  }
  for (int idx = gid; idx < (N_ * IN_) / 4; idx += gsz) {
    float4 v = ((const float4*)feat)[idx];
    short4 s4;
    s4.x = f2bf(v.x); s4.y = f2bf(v.y); s4.z = f2bf(v.z); s4.w = f2bf(v.w);
    ((short4*)feat_bf)[idx] = s4;
  }
  for (int idx = gid; idx < N_; idx += gsz) counts[idx] = 0;
  for (int idx = gid; idx < KTOT_; idx += gsz) counts2[idx] = 0;
}

// ---------------------------------------------------------------------------
// reorder (r5-verified mapping, now 17 slots): bake swizzled 16KB LDS stage
// tiles into w_relS so linear global_load_lds reproduces the ds_read image.
// ---------------------------------------------------------------------------
__global__ void reorder_kernel(const short* __restrict__ w_relT, short* __restrict__ w_relS) {
  int idx = blockIdx.x * 256 + threadIdx.x;
  if (idx >= (R_ + 1) * OUT_ * IN_) return;
  int r = idx >> 16;
  int rem = idx & 65535;
  int half = rem >> 15;
  int stage = (rem >> 13) & 3;
  int c = (rem >> 3) & 1023;
  int j = rem & 7;
  int scol = c >> 3;
  int q = (c & 7) ^ (scol & 7);
  int o = (half << 7) + scol;
  int i = (stage << 6) + (q << 3) + j;
  w_relS[idx] = w_relT[((r << 8) + o) * IN_ + i];
}

// ---------------------------------------------------------------------------
// hist: dst histogram (CSR) + (relation, src-bucket) histogram (gather sort)
// ---------------------------------------------------------------------------
__global__ void hist_kernel(const int* __restrict__ dst_idx, const int* __restrict__ src_idx,
                            int* __restrict__ counts, int* __restrict__ counts2) {
  int e = blockIdx.x * 256 + threadIdx.x;
  if (e < E_) {
    atomicAdd(&counts[dst_idx[e]], 1);
    int r = e / EPR_;
    atomicAdd(&counts2[r * NB_ + (src_idx[e] >> 7)], 1);
  }
}

// ---------------------------------------------------------------------------
// combined two-level exclusive scan over [counts[n]+1 (self slot) | counts2[k]]
// bucket offsets come out shifted by exactly E_+N_ (total of first section).
// ---------------------------------------------------------------------------
__global__ void scan1_kernel(const int* __restrict__ counts, const int* __restrict__ counts2,
                             int* __restrict__ offc, int* __restrict__ bsum) {
  __shared__ int tmp[256];
  int tid = threadIdx.x;
  int gid = blockIdx.x * 256 + tid;
  int v = (gid < N_) ? counts[gid] + 1 : (gid < SCN_ ? counts2[gid - N_] : 0);
  tmp[tid] = v;
  __syncthreads();
  for (int d = 1; d < 256; d <<= 1) {
    int add = (tid >= d) ? tmp[tid - d] : 0;
    __syncthreads();
    tmp[tid] += add;
    __syncthreads();
  }
  if (gid < SCN_) offc[gid] = tmp[tid] - v;       // exclusive
  if (tid == 255) bsum[blockIdx.x] = tmp[255];
}

__global__ void scan2_kernel(int* __restrict__ bsum) {
  __shared__ int tmp[256];
  int tid = threadIdx.x;
  int v = (tid < SCB_) ? bsum[tid] : 0;
  tmp[tid] = v;
  __syncthreads();
  for (int d = 1; d < 256; d <<= 1) {
    int add = (tid >= d) ? tmp[tid - d] : 0;
    __syncthreads();
    tmp[tid] += add;
    __syncthreads();
  }
  if (tid < SCB_) bsum[tid] = tmp[tid] - v;       // exclusive
}

__global__ void scan3_kernel(int* __restrict__ offc, const int* __restrict__ bsum,
                             int* __restrict__ woffc) {
  int gid = blockIdx.x * 256 + threadIdx.x;
  if (gid < SCN_) {
    int o = offc[gid] + bsum[blockIdx.x];
    offc[gid] = o;
    woffc[gid] = o + (gid < N_ ? 1 : 0);          // dst slot 0 reserved for self edge
  }
}

// scatter both: pos[e] = dst-CSR msg slot; esort = edges bucket-sorted by src
__global__ void scatter_kernel(const int* __restrict__ dst_idx, const int* __restrict__ src_idx,
                               int* __restrict__ woffc, int* __restrict__ pos,
                               int* __restrict__ esort) {
  int e = blockIdx.x * 256 + threadIdx.x;
  if (e < E_) {
    pos[e] = atomicAdd(&woffc[dst_idx[e]], 1);
    int r = e / EPR_;
    int k = r * NB_ + (src_idx[e] >> 7);
    int s = atomicAdd(&woffc[N_ + k], 1) - (E_ + N_);
    esort[s] = e;
  }
}

// ---------------------------------------------------------------------------
// edge (r8-verified GEMM core): tiles 0..R_*MBLK_-1 = relations (edges via
// esort, src-bucketed for gather locality); tiles >= R_*MBLK_ = selfloop
// pseudo-relation 16 (src=node, norm=1, msg slot = offc[node]).
// Bijective XCD-chunk swizzle keeps neighbor tiles + nhalf pairs on one XCD.
// MODE=0: nt bf16 msg stores; MODE=1: fp32 atomic fallback into acc_out.
// ---------------------------------------------------------------------------
template <int MODE>
__launch_bounds__(256)
__global__ void edge_kernel(const short* __restrict__ feat_bf, const short* __restrict__ w_relS,
                            const float* __restrict__ norm, const int* __restrict__ src_idx,
                            const int* __restrict__ dst_idx, const int* __restrict__ esort,
                            const int* __restrict__ pos, const int* __restrict__ offc,
                            short* __restrict__ msg, float* __restrict__ acc_out) {
  __shared__ short lds_b[2][128 * 64];   // 2 x 16KB double buffer
  // bijective XCD-chunk swizzle (m204): orig%8 -> contiguous logical chunk
  const int nwg = TIL_ * 2;              // 5806
  int xx = blockIdx.x & 7, oo = blockIdx.x >> 3;
  const int q = nwg >> 3, rr = nwg & 7;
  int wgid = (xx < rr ? xx * (q + 1) : rr * (q + 1) + (xx - rr) * q) + oo;
  int tile = wgid >> 1, nhalf = wgid & 1;
  int r, mblk;
  if (tile < R_ * MBLK_) { r = tile / MBLK_; mblk = tile - r * MBLK_; }
  else                   { r = R_;           mblk = tile - R_ * MBLK_; }
  const bool self = (r == R_);
  int base = self ? mblk * 128 : r * EPR_ + mblk * 128;
  int lim  = self ? N_ - mblk * 128 : EPR_ - mblk * 128;
  int rows = lim > 128 ? 128 : lim;

  int tid = threadIdx.x;
  int lane = tid & 63, wave = tid >> 6;
  int lm = lane & 31, hi = lane >> 5;
  int wr = wave << 5;

  int erow = wr + lm;
  int eg   = base + (erow < rows ? erow : 0);    // clamped: garbage rows never stored
  int src  = self ? eg : src_idx[esort[eg]];
  const bf16x8* __restrict__ arow = (const bf16x8*)(feat_bf + (size_t)src * IN_);

  // ---- prefetch the lane's full A half-row: 16 x 16B, all in flight at once
  bf16x8 a[16];
#pragma unroll
  for (int i = 0; i < 16; ++i) a[i] = arow[2 * i + hi];

  // ---- issue W stage tiles 0,1 (coalesced 1KB wave-chunks, linear LDS)
  const short* wt = w_relS + (size_t)(((r << 1) + nhalf) << 2) * 8192;
#pragma unroll
  for (int st = 0; st < 2; ++st) {
#pragma unroll
    for (int j = 0; j < 4; ++j) {
      int chunk = (wave << 2) + j;
      gl_lds16(wt + st * 8192 + chunk * 512 + lane * 8, &lds_b[st][chunk * 512]);
    }
  }

  f32x16 acc[4];
#pragma unroll
  for (int g = 0; g < 4; ++g)
#pragma unroll
    for (int t = 0; t < 16; ++t) acc[g][t] = 0.f;

  __syncthreads();   // drains A regs + W0/W1 (vmcnt(0) + barrier)

#pragma unroll
  for (int stage = 0; stage < 4; ++stage) {
    const short* lb = lds_b[stage & 1];
#pragma unroll
    for (int s = 0; s < 4; ++s) {
      bf16x8 af = a[stage * 4 + s];
      int qq = s * 2 + hi;
#pragma unroll
      for (int g = 0; g < 4; ++g) {
        int col = (g << 5) + lm;
        bf16x8 bfr = *(const bf16x8*)(&lb[col * 64 + ((qq ^ (col & 7)) << 3)]);
        acc[g] = __builtin_amdgcn_mfma_f32_32x32x16_bf16(af, bfr, acc[g], 0, 0, 0);
      }
    }
    __syncthreads();   // all waves done reading buf[stage&1]; drains next-stage loads
    if (stage < 2) {
#pragma unroll
      for (int j = 0; j < 4; ++j) {
        int chunk = (wave << 2) + j;
        gl_lds16(wt + (stage + 2) * 8192 + chunk * 512 + lane * 8,
                 &lds_b[stage & 1][chunk * 512]);
      }
    }
  }

  // ---- epilogue: row t = edge/node, col = channel (r4-verified mapping)
  float nr[16]; int er_ok[16]; int prow[16]; int db[16];
#pragma unroll
  for (int t = 0; t < 16; ++t) {
    int row = (t & 3) + ((t >> 2) << 3) + (hi << 2);
    int er  = wr + row;
    int ee  = base + (er < rows ? er : 0);
    er_ok[t] = (er < rows);
    if (self) {
      nr[t] = 1.f;
      prow[t] = offc[ee];
      db[t] = ee * OUT_;
    } else {
      int em = esort[ee];
      nr[t]   = norm[em];
      prow[t] = (MODE == 0) ? pos[em] : 0;
      db[t]   = dst_idx[em] * OUT_;
    }
  }
#pragma unroll
  for (int g = 0; g < 4; ++g) {
    int col = nhalf * 128 + (g << 5) + lm;
#pragma unroll
    for (int t = 0; t < 16; ++t) {
      if (er_ok[t]) {
        float v = acc[g][t] * nr[t];
        if (MODE == 0)
          __builtin_nontemporal_store(f2bf(v), &msg[(size_t)prow[t] * OUT_ + col]);
        else
          unsafeAtomicAdd(&acc_out[(size_t)db[t] + col], v);
      }
    }
  }
}

// ---------------------------------------------------------------------------
// agg: node's CSR range = [offc[n], offc[n]+counts[n]+1) incl. self row.
// Streaming reads; fp32 accumulate; + bias, ReLU, final out write.
// ---------------------------------------------------------------------------
__launch_bounds__(256)
__global__ void agg_kernel(const short* __restrict__ msg, const int* __restrict__ offc,
                           const int* __restrict__ counts, const float* __restrict__ h_bias,
                           float* __restrict__ out) {
  int n = blockIdx.x * 4 + (threadIdx.x >> 6);
  if (n >= N_) return;
  int lane = threadIdx.x & 63;
  int off = offc[n], cnt = counts[n] + 1;
  float4 a = make_float4(0.f, 0.f, 0.f, 0.f);
  const unsigned long long* __restrict__ m8 = (const unsigned long long*)msg; // row = 64 x 8B
  for (int j = 0; j < cnt; ++j) {
    unsigned long long v = __builtin_nontemporal_load(&m8[(size_t)(off + j) * 64 + lane]);
    a.x += bf2f((unsigned short)(v & 0xffffu));
    a.y += bf2f((unsigned short)((v >> 16) & 0xffffu));
    a.z += bf2f((unsigned short)((v >> 32) & 0xffffu));
    a.w += bf2f((unsigned short)(v >> 48));
  }
  float4 b = ((const float4*)h_bias)[lane];
  a.x = fmaxf(a.x + b.x, 0.f);
  a.y = fmaxf(a.y + b.y, 0.f);
  a.z = fmaxf(a.z + b.z, 0.f);
  a.w = fmaxf(a.w + b.w, 0.f);
  ((float4*)out)[(size_t)n * 64 + lane] = a;
}

// fallback helpers
__global__ void zero_out_kernel(float* __restrict__ out) {
  int idx = blockIdx.x * 256 + threadIdx.x;
  if (idx < N_ * OUT_ / 4)
    ((float4*)out)[idx] = make_float4(0.f, 0.f, 0.f, 0.f);
}
__global__ void bias_relu_kernel(float* __restrict__ out, const float* __restrict__ h_bias) {
  int idx = blockIdx.x * 256 + threadIdx.x;
  if (idx < N_ * OUT_ / 4) {
    float4 v = ((float4*)out)[idx];
    float4 b = ((const float4*)h_bias)[idx & 63];
    v.x = fmaxf(v.x + b.x, 0.f);
    v.y = fmaxf(v.y + b.y, 0.f);
    v.z = fmaxf(v.z + b.z, 0.f);
    v.w = fmaxf(v.w + b.w, 0.f);
    ((float4*)out)[idx] = v;
  }
}

// ---------------------------------------------------------------------------
extern "C" void kernel_launch(void* const* d_in, const int* in_sizes, int n_in,
                              void* d_out, int out_size, void* d_ws, size_t ws_size,
                              hipStream_t stream) {
  const float* feat    = (const float*)d_in[0];
  const float* weight  = (const float*)d_in[1];
  const float* w_comp  = (const float*)d_in[2];
  const float* loop_w  = (const float*)d_in[3];
  const float* h_bias  = (const float*)d_in[4];
  const float* norm    = (const float*)d_in[5];
  const int*   src_idx = (const int*)d_in[6];
  const int*   dst_idx = (const int*)d_in[7];
  float* out = (float*)d_out;

  short* w_relT  = (short*)d_ws;                        // 17 slots = 2.23 MB
  short* w_relS  = w_relT + (R_ + 1) * OUT_ * IN_;      // 2.23 MB
  short* feat_bf = w_relS + (R_ + 1) * OUT_ * IN_;      // 25.6 MB
  int*   counts  = (int*)(feat_bf + (size_t)N_ * IN_);  // 200 KB
  int*   counts2 = counts + N_;                         // 25 KB
  int*   offc    = counts2 + KTOT_;                     // 225 KB
  int*   woffc   = offc + SCN_;                         // 225 KB
  int*   bsum    = woffc + SCN_;                        // 1 KB
  int*   pos     = bsum + 256;                          // 1.28 MB
  int*   esort   = pos + E_;                            // 1.28 MB
  short* msg     = (short*)(esort + E_);                // (E+N)*256 bf16 = 189.4 MB
  size_t need    = (size_t)((char*)(msg + (size_t)(E_ + N_) * OUT_) - (char*)d_ws);

  prep_kernel<<<1024, 256, 0, stream>>>(feat, weight, w_comp, loop_w,
                                        w_relT, feat_bf, counts, counts2);
  reorder_kernel<<<((R_ + 1) * OUT_ * IN_) / 256, 256, 0, stream>>>(w_relT, w_relS);
  hist_kernel<<<(E_ + 255) / 256, 256, 0, stream>>>(dst_idx, src_idx, counts, counts2);
  scan1_kernel<<<SCB_, 256, 0, stream>>>(counts, counts2, offc, bsum);
  scan2_kernel<<<1, 256, 0, stream>>>(bsum);
  scan3_kernel<<<SCB_, 256, 0, stream>>>(offc, bsum, woffc);
  scatter_kernel<<<(E_ + 255) / 256, 256, 0, stream>>>(dst_idx, src_idx, woffc, pos, esort);

  if (ws_size >= need) {
    edge_kernel<0><<<TIL_ * 2, 256, 0, stream>>>(feat_bf, w_relS, norm, src_idx, dst_idx,
                                                 esort, pos, offc, msg, nullptr);
    agg_kernel<<<(N_ + 3) / 4, 256, 0, stream>>>(msg, offc, counts, h_bias, out);
  } else {
    // fallback: fp32 atomic scatter (incl. selfloop pseudo-relation), then bias+relu
    zero_out_kernel<<<(N_ * OUT_ / 4 + 255) / 256, 256, 0, stream>>>(out);
    edge_kernel<1><<<TIL_ * 2, 256, 0, stream>>>(feat_bf, w_relS, norm, src_idx, dst_idx,
                                                 esort, nullptr, offc, nullptr, out);
    bias_relu_kernel<<<(N_ * OUT_ / 4 + 255) / 256, 256, 0, stream>>>(out, h_bias);
  }
}

// Round 11
// 256.958 us; speedup vs baseline: 1.0675x; 1.0675x over previous
//
#include <hip/hip_runtime.h>

#define N_    50000
#define E_    320000
#define R_    16
#define B_    8
#define IN_   256
#define OUT_  256
#define EPR_  (E_ / R_)      // 20000 edges per relation
#define MBLK_ 157            // ceil(EPR_/128)
#define NBLK_ 391            // ceil(N_/128)
#define SBLK_ 196            // ceil(N_/256) scan blocks

typedef float  f32x16 __attribute__((ext_vector_type(16)));
typedef __bf16 bf16x8 __attribute__((ext_vector_type(8)));

static __device__ __forceinline__ short f2bf(float f) {
  unsigned u = __float_as_uint(f);
  u = (u + 0x7FFFu + ((u >> 16) & 1u)) >> 16;   // RNE
  return (short)u;
}
static __device__ __forceinline__ float bf2f(unsigned short s) {
  return __uint_as_float(((unsigned)s) << 16);
}

// async global->LDS, 16B per lane; LDS dest = wave-uniform base + lane*16
static __device__ __forceinline__ void gl_lds16(const short* g, short* l) {
  __builtin_amdgcn_global_load_lds(
      (const __attribute__((address_space(1))) void*)g,
      (__attribute__((address_space(3))) void*)l, 16, 0, 0);
}

// ---------------------------------------------------------------------------
// prep: w_relT[r][o][i] = sum_b w_comp[r,b]*weight[b,i,o]  (bf16, transposed)
//       loopT[o][i] = loop_weight[i][o] (bf16), feat -> bf16 (RNE), zero counts
// ---------------------------------------------------------------------------
__global__ void prep_kernel(const float* __restrict__ feat, const float* __restrict__ weight,
                            const float* __restrict__ w_comp, const float* __restrict__ loop_w,
                            short* __restrict__ w_relT, short* __restrict__ loopT,
                            short* __restrict__ feat_bf, int* __restrict__ counts) {
  int gid = blockIdx.x * blockDim.x + threadIdx.x;
  int gsz = gridDim.x * blockDim.x;
  for (int idx = gid; idx < R_ * OUT_ * IN_; idx += gsz) {
    int r = idx >> 16, i = (idx >> 8) & 255, o = idx & 255;  // o fastest: coalesced weight reads
    float s = 0.f;
#pragma unroll
    for (int b = 0; b < B_; ++b)
      s += w_comp[r * B_ + b] * weight[(b * IN_ + i) * OUT_ + o];
    w_relT[(r * OUT_ + o) * IN_ + i] = f2bf(s);
  }
  for (int idx = gid; idx < OUT_ * IN_; idx += gsz) {
    int i = idx >> 8, o = idx & 255;
    loopT[o * IN_ + i] = f2bf(loop_w[i * OUT_ + o]);
  }
  for (int idx = gid; idx < (N_ * IN_) / 4; idx += gsz) {
    float4 v = ((const float4*)feat)[idx];
    short4 s4;
    s4.x = f2bf(v.x); s4.y = f2bf(v.y); s4.z = f2bf(v.z); s4.w = f2bf(v.w);
    ((short4*)feat_bf)[idx] = s4;
  }
  for (int idx = gid; idx < N_; idx += gsz) counts[idx] = 0;
}

// ---------------------------------------------------------------------------
// reorder (EXACT r5/r9): bake the swizzled 16KB LDS stage-tiles into w_relS so
// global_load_lds (linear LDS write) reproduces the verified ds_read image.
// The 4 stage tiles of one (r,half) are contiguous -> one 64KB linear load.
// ---------------------------------------------------------------------------
__global__ void reorder_kernel(const short* __restrict__ w_relT, short* __restrict__ w_relS) {
  int idx = blockIdx.x * 256 + threadIdx.x;
  if (idx >= R_ * OUT_ * IN_) return;
  int r = idx >> 16;
  int rem = idx & 65535;
  int half = rem >> 15;
  int stage = (rem >> 13) & 3;
  int c = (rem >> 3) & 1023;
  int j = rem & 7;
  int scol = c >> 3;
  int q = (c & 7) ^ (scol & 7);
  int o = (half << 7) + scol;
  int i = (stage << 6) + (q << 3) + j;
  w_relS[idx] = w_relT[((r << 8) + o) * IN_ + i];
}

// ---------------------------------------------------------------------------
// CSR build: histogram -> two-level scan (3 small kernels) -> scatter pos
// ---------------------------------------------------------------------------
__global__ void hist_kernel(const int* __restrict__ dst_idx, int* __restrict__ counts) {
  int e = blockIdx.x * 256 + threadIdx.x;
  if (e < E_) atomicAdd(&counts[dst_idx[e]], 1);
}

__global__ void scan1_kernel(const int* __restrict__ counts, int* __restrict__ offsets,
                             int* __restrict__ bsum) {
  __shared__ int tmp[256];
  int tid = threadIdx.x;
  int gid = blockIdx.x * 256 + tid;
  int v = (gid < N_) ? counts[gid] : 0;
  tmp[tid] = v;
  __syncthreads();
  for (int d = 1; d < 256; d <<= 1) {
    int add = (tid >= d) ? tmp[tid - d] : 0;
    __syncthreads();
    tmp[tid] += add;
    __syncthreads();
  }
  if (gid < N_) offsets[gid] = tmp[tid] - v;      // exclusive
  if (tid == 255) bsum[blockIdx.x] = tmp[255];    // block total
}

__global__ void scan2_kernel(int* __restrict__ bsum) {
  __shared__ int tmp[256];
  int tid = threadIdx.x;
  int v = (tid < SBLK_) ? bsum[tid] : 0;
  tmp[tid] = v;
  __syncthreads();
  for (int d = 1; d < 256; d <<= 1) {
    int add = (tid >= d) ? tmp[tid - d] : 0;
    __syncthreads();
    tmp[tid] += add;
    __syncthreads();
  }
  if (tid < SBLK_) bsum[tid] = tmp[tid] - v;      // exclusive
}

__global__ void scan3_kernel(int* __restrict__ offsets, const int* __restrict__ bsum,
                             int* __restrict__ woff) {
  int gid = blockIdx.x * 256 + threadIdx.x;
  if (gid < N_) {
    int o = offsets[gid] + bsum[blockIdx.x];
    offsets[gid] = o;
    woff[gid] = o;
  }
}

__global__ void scatter_kernel(const int* __restrict__ dst_idx, int* __restrict__ woff,
                               int* __restrict__ pos) {
  int e = blockIdx.x * 256 + threadIdx.x;
  if (e < E_) {
    int p = atomicAdd(&woff[dst_idx[e]], 1);
    pos[e] = p;        // CSR slot of edge e (msg row index)
  }
}

// ---------------------------------------------------------------------------
// edge (r9 numerics, SINGLE-BARRIER structure): full 64KB W-half loaded once
// via global_load_lds; A row prefetched to 16 regs; ONE __syncthreads; then
// all 64 MFMAs with no further barriers. 4 latency exposures -> 1.
// MODE=0: nt bf16 stores to CSR-permuted msg rows; MODE=1: fp32 atomic fallback.
// ---------------------------------------------------------------------------
template <int MODE>
__launch_bounds__(256)
__global__ void edge_kernel(const short* __restrict__ feat_bf, const short* __restrict__ w_relS,
                            const float* __restrict__ norm, const int* __restrict__ src_idx,
                            const int* __restrict__ dst_idx, const int* __restrict__ pos,
                            short* __restrict__ msg, float* __restrict__ acc_out) {
  __shared__ short lds_w[4 * 8192];      // 64KB: all 4 stage-tiles of this (r,half)
  int bid  = blockIdx.x;
  int r    = bid / (MBLK_ * 2);
  int rem  = bid - r * (MBLK_ * 2);
  int mblk = rem >> 1, nhalf = rem & 1;
  int e0   = r * EPR_ + mblk * 128;
  int rows = EPR_ - mblk * 128; if (rows > 128) rows = 128;

  int tid = threadIdx.x;
  int lane = tid & 63, wave = tid >> 6;
  int lm = lane & 31, hi = lane >> 5;
  int wr = wave << 5;

  int erow = wr + lm;
  int eg   = e0 + (erow < rows ? erow : 0);      // clamped: garbage rows never stored
  int src  = src_idx[eg];
  const bf16x8* __restrict__ arow = (const bf16x8*)(feat_bf + (size_t)src * IN_);

  // ---- prefetch the lane's full A half-row: 16 x 16B, all in flight at once
  bf16x8 a[16];
#pragma unroll
  for (int i = 0; i < 16; ++i) a[i] = arow[2 * i + hi];

  // ---- issue the FULL W-half (64KB = 64 x 1KB wave-chunks), linear LDS
  const short* wt = w_relS + (size_t)(((r << 1) + nhalf) << 2) * 8192;
#pragma unroll
  for (int j = 0; j < 16; ++j) {
    int chunk = (wave << 4) + j;
    gl_lds16(wt + chunk * 512 + lane * 8, &lds_w[chunk * 512]);
  }

  f32x16 acc[4];
#pragma unroll
  for (int g = 0; g < 4; ++g)
#pragma unroll
    for (int t = 0; t < 16; ++t) acc[g][t] = 0.f;

  __syncthreads();   // the ONLY barrier: drains A regs + whole W (vmcnt(0))

#pragma unroll
  for (int stage = 0; stage < 4; ++stage) {
    const short* lb = &lds_w[stage * 8192];
#pragma unroll
    for (int s = 0; s < 4; ++s) {
      bf16x8 af = a[stage * 4 + s];
      int q = s * 2 + hi;
#pragma unroll
      for (int g = 0; g < 4; ++g) {
        int col = (g << 5) + lm;
        bf16x8 bfr = *(const bf16x8*)(&lb[col * 64 + ((q ^ (col & 7)) << 3)]);
        acc[g] = __builtin_amdgcn_mfma_f32_32x32x16_bf16(af, bfr, acc[g], 0, 0, 0);
      }
    }
  }

  // ---- epilogue: row t = edge, col = channel (r4-verified mapping)
  float nr[16]; int er_ok[16]; int prow[16]; int db[16];
#pragma unroll
  for (int t = 0; t < 16; ++t) {
    int row = (t & 3) + ((t >> 2) << 3) + (hi << 2);
    int er  = wr + row;
    int ee  = e0 + (er < rows ? er : 0);
    nr[t]    = norm[ee];
    er_ok[t] = (er < rows);
    prow[t]  = (MODE == 0) ? pos[ee] : 0;
    db[t]    = dst_idx[ee] * OUT_;
  }
#pragma unroll
  for (int g = 0; g < 4; ++g) {
    int col = nhalf * 128 + (g << 5) + lm;
#pragma unroll
    for (int t = 0; t < 16; ++t) {
      if (er_ok[t]) {
        float v = acc[g][t] * nr[t];
        if (MODE == 0)
          __builtin_nontemporal_store(f2bf(v), &msg[(size_t)prow[t] * OUT_ + col]);
        else
          unsafeAtomicAdd(&acc_out[(size_t)db[t] + col], v);
      }
    }
  }
}

// ---------------------------------------------------------------------------
// agg: msg rows are CSR-ordered -> perfectly streaming reads.
// One wave per node; lane owns 4 channels; fp32 register accumulation.
// ---------------------------------------------------------------------------
__launch_bounds__(256)
__global__ void agg_kernel(const short* __restrict__ msg, const int* __restrict__ offsets,
                           const int* __restrict__ counts, float* __restrict__ out) {
  int n = blockIdx.x * 4 + (threadIdx.x >> 6);
  if (n >= N_) return;
  int lane = threadIdx.x & 63;
  int off = offsets[n], cnt = counts[n];
  float4 a = make_float4(0.f, 0.f, 0.f, 0.f);
  const unsigned long long* __restrict__ m8 = (const unsigned long long*)msg; // row = 64 x 8B
  for (int j = 0; j < cnt; ++j) {
    unsigned long long v = __builtin_nontemporal_load(&m8[(size_t)(off + j) * 64 + lane]);
    a.x += bf2f((unsigned short)(v & 0xffffu));
    a.y += bf2f((unsigned short)((v >> 16) & 0xffffu));
    a.z += bf2f((unsigned short)((v >> 32) & 0xffffu));
    a.w += bf2f((unsigned short)(v >> 48));
  }
  ((float4*)out)[(size_t)n * 64 + lane] = a;
}

__global__ void zero_out_kernel(float* __restrict__ out) {
  int idx = blockIdx.x * 256 + threadIdx.x;
  if (idx < N_ * OUT_ / 4)
    ((float4*)out)[idx] = make_float4(0.f, 0.f, 0.f, 0.f);
}

// ---------------------------------------------------------------------------
// selfloop (EXACT r9/r1): out = relu(out + h_bias + feat @ loop_weight)
// ---------------------------------------------------------------------------
__launch_bounds__(256)
__global__ void selfloop_kernel(const short* __restrict__ feat_bf, const short* __restrict__ loopT,
                                const float* __restrict__ h_bias, float* __restrict__ inout) {
  __shared__ short lds_b[128 * 64];
  int bid = blockIdx.x;
  int mblk = bid >> 1, nhalf = bid & 1;
  int n0 = mblk << 7;
  int rows = N_ - n0; if (rows > 128) rows = 128;

  int tid = threadIdx.x;
  int lane = tid & 63, wave = tid >> 6;
  int lm = lane & 31, hi = lane >> 5;
  int wr = wave << 5;

  int nrow = wr + lm;
  int ng = n0 + (nrow < rows ? nrow : 0);
  const bf16x8* __restrict__ arow = (const bf16x8*)(feat_bf + (size_t)ng * IN_);
  const short*  __restrict__ wb   = loopT + nhalf * 128 * IN_;

  f32x16 acc[4];
#pragma unroll
  for (int g = 0; g < 4; ++g)
#pragma unroll
    for (int t = 0; t < 16; ++t) acc[g][t] = 0.f;

  int scol = tid >> 1, sh = tid & 1;
  const bf16x8* __restrict__ gsrc0 = (const bf16x8*)(wb + scol * IN_ + sh * 32);

  for (int stage = 0; stage < 4; ++stage) {
#pragma unroll
    for (int c8 = 0; c8 < 4; ++c8) {
      int q = sh * 4 + c8;
      bf16x8 v = gsrc0[stage * 8 + c8];
      *(bf16x8*)(&lds_b[scol * 64 + ((q ^ (scol & 7)) << 3)]) = v;
    }
    bf16x8 af[4];
#pragma unroll
    for (int s = 0; s < 4; ++s) af[s] = arow[stage * 8 + s * 2 + hi];
    __syncthreads();
#pragma unroll
    for (int s = 0; s < 4; ++s) {
      int q = s * 2 + hi;
#pragma unroll
      for (int g = 0; g < 4; ++g) {
        int col = (g << 5) + lm;
        bf16x8 bfr = *(const bf16x8*)(&lds_b[col * 64 + ((q ^ (col & 7)) << 3)]);
        acc[g] = __builtin_amdgcn_mfma_f32_32x32x16_bf16(af[s], bfr, acc[g], 0, 0, 0);
      }
    }
    __syncthreads();
  }

#pragma unroll
  for (int g = 0; g < 4; ++g) {
    int col = nhalf * 128 + (g << 5) + lm;
    float hb = h_bias[col];
#pragma unroll
    for (int t = 0; t < 16; ++t) {
      int row = (t & 3) + ((t >> 2) << 3) + (hi << 2);
      int nn = wr + row;
      if (nn < rows) {
        size_t off = (size_t)(n0 + nn) * OUT_ + col;
        float x = inout[off] + acc[g][t] + hb;
        inout[off] = x > 0.f ? x : 0.f;
      }
    }
  }
}

// ---------------------------------------------------------------------------
extern "C" void kernel_launch(void* const* d_in, const int* in_sizes, int n_in,
                              void* d_out, int out_size, void* d_ws, size_t ws_size,
                              hipStream_t stream) {
  const float* feat    = (const float*)d_in[0];
  const float* weight  = (const float*)d_in[1];
  const float* w_comp  = (const float*)d_in[2];
  const float* loop_w  = (const float*)d_in[3];
  const float* h_bias  = (const float*)d_in[4];
  const float* norm    = (const float*)d_in[5];
  const int*   src_idx = (const int*)d_in[6];
  const int*   dst_idx = (const int*)d_in[7];
  float* out = (float*)d_out;

  short* w_relT  = (short*)d_ws;                 // 2 MB
  short* w_relS  = w_relT + R_ * OUT_ * IN_;     // 2 MB (pre-swizzled LDS image)
  short* loopT   = w_relS + R_ * OUT_ * IN_;     // 128 KB
  short* feat_bf = loopT + OUT_ * IN_;           // 25.6 MB
  int*   counts  = (int*)(feat_bf + (size_t)N_ * IN_);  // 200 KB
  int*   offsets = counts + N_;                  // 200 KB
  int*   woff    = offsets + N_;                 // 200 KB
  int*   bsum    = woff + N_;                    // 1 KB (scan block sums)
  int*   pos     = bsum + 256;                   // 1.28 MB (edge -> CSR slot)
  short* msg     = (short*)(pos + E_);           // 163.84 MB (bf16, CSR-ordered)
  size_t need    = (size_t)((char*)(msg + (size_t)E_ * OUT_) - (char*)d_ws);

  prep_kernel<<<1024, 256, 0, stream>>>(feat, weight, w_comp, loop_w,
                                        w_relT, loopT, feat_bf, counts);
  reorder_kernel<<<(R_ * OUT_ * IN_) / 256, 256, 0, stream>>>(w_relT, w_relS);

  if (ws_size >= need) {
    // CSR path: permuted bf16 msg (nt stores), streaming aggregation
    hist_kernel<<<(E_ + 255) / 256, 256, 0, stream>>>(dst_idx, counts);
    scan1_kernel<<<SBLK_, 256, 0, stream>>>(counts, offsets, bsum);
    scan2_kernel<<<1, 256, 0, stream>>>(bsum);
    scan3_kernel<<<SBLK_, 256, 0, stream>>>(offsets, bsum, woff);
    scatter_kernel<<<(E_ + 255) / 256, 256, 0, stream>>>(dst_idx, woff, pos);
    edge_kernel<0><<<MBLK_ * 2 * R_, 256, 0, stream>>>(feat_bf, w_relS, norm, src_idx, dst_idx,
                                                       pos, msg, nullptr);
    agg_kernel<<<(N_ + 3) / 4, 256, 0, stream>>>(msg, offsets, counts, out);
  } else {
    // fallback: fp32 atomic scatter
    zero_out_kernel<<<(N_ * OUT_ / 4 + 255) / 256, 256, 0, stream>>>(out);
    edge_kernel<1><<<MBLK_ * 2 * R_, 256, 0, stream>>>(feat_bf, w_relS, norm, src_idx, dst_idx,
                                                       nullptr, nullptr, out);
  }

  selfloop_kernel<<<NBLK_ * 2, 256, 0, stream>>>(feat_bf, loopT, h_bias, out);
}

// Round 12
// 235.718 us; speedup vs baseline: 1.1637x; 1.0901x over previous
//
#include <hip/hip_runtime.h>

#define N_    50000
#define E_    320000
#define R_    16
#define B_    8
#define IN_   256
#define OUT_  256
#define EPR_  (E_ / R_)      // 20000 edges per relation
#define MBLK_ 157            // ceil(EPR_/128)
#define NBLK_ 391            // ceil(N_/128)
#define SBLK_ 196            // ceil(N_/256) scan blocks

typedef float  f32x16 __attribute__((ext_vector_type(16)));
typedef __bf16 bf16x8 __attribute__((ext_vector_type(8)));

static __device__ __forceinline__ short f2bf(float f) {
  unsigned u = __float_as_uint(f);
  u = (u + 0x7FFFu + ((u >> 16) & 1u)) >> 16;   // RNE
  return (short)u;
}
static __device__ __forceinline__ float bf2f(unsigned short s) {
  return __uint_as_float(((unsigned)s) << 16);
}

// async global->LDS, 16B per lane; LDS dest = wave-uniform base + lane*16
static __device__ __forceinline__ void gl_lds16(const short* g, short* l) {
  __builtin_amdgcn_global_load_lds(
      (const __attribute__((address_space(1))) void*)g,
      (__attribute__((address_space(3))) void*)l, 16, 0, 0);
}

// ---------------------------------------------------------------------------
// prep: w_relT[r][o][i] = sum_b w_comp[r,b]*weight[b,i,o]  (bf16, transposed)
//       loopT[o][i] = loop_weight[i][o] (bf16), feat -> bf16 (RNE), zero counts
// ---------------------------------------------------------------------------
__global__ void prep_kernel(const float* __restrict__ feat, const float* __restrict__ weight,
                            const float* __restrict__ w_comp, const float* __restrict__ loop_w,
                            short* __restrict__ w_relT, short* __restrict__ loopT,
                            short* __restrict__ feat_bf, int* __restrict__ counts) {
  int gid = blockIdx.x * blockDim.x + threadIdx.x;
  int gsz = gridDim.x * blockDim.x;
  for (int idx = gid; idx < R_ * OUT_ * IN_; idx += gsz) {
    int r = idx >> 16, i = (idx >> 8) & 255, o = idx & 255;  // o fastest: coalesced weight reads
    float s = 0.f;
#pragma unroll
    for (int b = 0; b < B_; ++b)
      s += w_comp[r * B_ + b] * weight[(b * IN_ + i) * OUT_ + o];
    w_relT[(r * OUT_ + o) * IN_ + i] = f2bf(s);
  }
  for (int idx = gid; idx < OUT_ * IN_; idx += gsz) {
    int i = idx >> 8, o = idx & 255;
    loopT[o * IN_ + i] = f2bf(loop_w[i * OUT_ + o]);
  }
  for (int idx = gid; idx < (N_ * IN_) / 4; idx += gsz) {
    float4 v = ((const float4*)feat)[idx];
    short4 s4;
    s4.x = f2bf(v.x); s4.y = f2bf(v.y); s4.z = f2bf(v.z); s4.w = f2bf(v.w);
    ((short4*)feat_bf)[idx] = s4;
  }
  for (int idx = gid; idx < N_; idx += gsz) counts[idx] = 0;
}

// ---------------------------------------------------------------------------
// reorder (EXACT r5/r9): bake the swizzled 16KB LDS stage-tiles into w_relS so
// global_load_lds (linear LDS write) reproduces the verified ds_read image.
// The 4 stage tiles of one (r,half) are contiguous -> one 64KB linear load.
// ---------------------------------------------------------------------------
__global__ void reorder_kernel(const short* __restrict__ w_relT, short* __restrict__ w_relS) {
  int idx = blockIdx.x * 256 + threadIdx.x;
  if (idx >= R_ * OUT_ * IN_) return;
  int r = idx >> 16;
  int rem = idx & 65535;
  int half = rem >> 15;
  int stage = (rem >> 13) & 3;
  int c = (rem >> 3) & 1023;
  int j = rem & 7;
  int scol = c >> 3;
  int q = (c & 7) ^ (scol & 7);
  int o = (half << 7) + scol;
  int i = (stage << 6) + (q << 3) + j;
  w_relS[idx] = w_relT[((r << 8) + o) * IN_ + i];
}

// ---------------------------------------------------------------------------
// CSR build: histogram -> two-level scan (3 small kernels) -> scatter pos
// ---------------------------------------------------------------------------
__global__ void hist_kernel(const int* __restrict__ dst_idx, int* __restrict__ counts) {
  int e = blockIdx.x * 256 + threadIdx.x;
  if (e < E_) atomicAdd(&counts[dst_idx[e]], 1);
}

__global__ void scan1_kernel(const int* __restrict__ counts, int* __restrict__ offsets,
                             int* __restrict__ bsum) {
  __shared__ int tmp[256];
  int tid = threadIdx.x;
  int gid = blockIdx.x * 256 + tid;
  int v = (gid < N_) ? counts[gid] : 0;
  tmp[tid] = v;
  __syncthreads();
  for (int d = 1; d < 256; d <<= 1) {
    int add = (tid >= d) ? tmp[tid - d] : 0;
    __syncthreads();
    tmp[tid] += add;
    __syncthreads();
  }
  if (gid < N_) offsets[gid] = tmp[tid] - v;      // exclusive
  if (tid == 255) bsum[blockIdx.x] = tmp[255];    // block total
}

__global__ void scan2_kernel(int* __restrict__ bsum) {
  __shared__ int tmp[256];
  int tid = threadIdx.x;
  int v = (tid < SBLK_) ? bsum[tid] : 0;
  tmp[tid] = v;
  __syncthreads();
  for (int d = 1; d < 256; d <<= 1) {
    int add = (tid >= d) ? tmp[tid - d] : 0;
    __syncthreads();
    tmp[tid] += add;
    __syncthreads();
  }
  if (tid < SBLK_) bsum[tid] = tmp[tid] - v;      // exclusive
}

__global__ void scan3_kernel(int* __restrict__ offsets, const int* __restrict__ bsum,
                             int* __restrict__ woff) {
  int gid = blockIdx.x * 256 + threadIdx.x;
  if (gid < N_) {
    int o = offsets[gid] + bsum[blockIdx.x];
    offsets[gid] = o;
    woff[gid] = o;
  }
}

__global__ void scatter_kernel(const int* __restrict__ dst_idx, int* __restrict__ woff,
                               int* __restrict__ pos) {
  int e = blockIdx.x * 256 + threadIdx.x;
  if (e < E_) {
    int p = atomicAdd(&woff[dst_idx[e]], 1);
    pos[e] = p;        // CSR slot of edge e (msg row index)
  }
}

// ---------------------------------------------------------------------------
// edge (r11 numerics, FULL-ROW blocks): one block per 128 edges computes BOTH
// 128-col halves sequentially, gathering each feat row ONCE (halves the
// random-gather request count, the surviving bottleneck suspect).
//   gather A -> regs; stage W(h=0) 64KB -> LDS; barrier; MFMA+stores h=0;
//   barrier; stage W(h=1) into same LDS; barrier; MFMA+stores h=1.
// MODE=0: nt bf16 stores to CSR-permuted msg rows; MODE=1: fp32 atomic fallback.
// ---------------------------------------------------------------------------
template <int MODE>
__launch_bounds__(256)
__global__ void edge_kernel(const short* __restrict__ feat_bf, const short* __restrict__ w_relS,
                            const float* __restrict__ norm, const int* __restrict__ src_idx,
                            const int* __restrict__ dst_idx, const int* __restrict__ pos,
                            short* __restrict__ msg, float* __restrict__ acc_out) {
  __shared__ short lds_w[4 * 8192];      // 64KB: the 4 stage-tiles of one (r,half)
  int bid  = blockIdx.x;
  int r    = bid / MBLK_;
  int mblk = bid - r * MBLK_;
  int e0   = r * EPR_ + mblk * 128;
  int rows = EPR_ - mblk * 128; if (rows > 128) rows = 128;

  int tid = threadIdx.x;
  int lane = tid & 63, wave = tid >> 6;
  int lm = lane & 31, hi = lane >> 5;
  int wr = wave << 5;

  int erow = wr + lm;
  int eg   = e0 + (erow < rows ? erow : 0);      // clamped: garbage rows never stored
  int src  = src_idx[eg];
  const bf16x8* __restrict__ arow = (const bf16x8*)(feat_bf + (size_t)src * IN_);

  // ---- gather the lane's A half-row ONCE: 16 x 16B, all in flight at once
  bf16x8 a[16];
#pragma unroll
  for (int i = 0; i < 16; ++i) a[i] = arow[2 * i + hi];

  // ---- epilogue metadata (shared by both halves)
  float nr[16]; int er_ok[16]; int prow[16]; int db[16];
#pragma unroll
  for (int t = 0; t < 16; ++t) {
    int row = (t & 3) + ((t >> 2) << 3) + (hi << 2);
    int er  = wr + row;
    int ee  = e0 + (er < rows ? er : 0);
    nr[t]    = norm[ee];
    er_ok[t] = (er < rows);
    prow[t]  = (MODE == 0) ? pos[ee] : 0;
    db[t]    = dst_idx[ee] * OUT_;
  }

  const short* wt = w_relS + (size_t)(r << 1) * 32768;   // halves contiguous: +h*32768

#pragma unroll
  for (int h = 0; h < 2; ++h) {
    // ---- stage W half h (64KB = 64 x 1KB wave-chunks), linear LDS
    if (h == 1) __syncthreads();        // all waves done reading lds_w (half 0)
#pragma unroll
    for (int j = 0; j < 16; ++j) {
      int chunk = (wave << 4) + j;
      gl_lds16(wt + h * 32768 + chunk * 512 + lane * 8, &lds_w[chunk * 512]);
    }

    f32x16 acc[4];
#pragma unroll
    for (int g = 0; g < 4; ++g)
#pragma unroll
      for (int t = 0; t < 16; ++t) acc[g][t] = 0.f;

    __syncthreads();                    // drains A regs (h=0) + W half h

#pragma unroll
    for (int stage = 0; stage < 4; ++stage) {
      const short* lb = &lds_w[stage * 8192];
#pragma unroll
      for (int s = 0; s < 4; ++s) {
        bf16x8 af = a[stage * 4 + s];
        int q = s * 2 + hi;
#pragma unroll
        for (int g = 0; g < 4; ++g) {
          int col = (g << 5) + lm;
          bf16x8 bfr = *(const bf16x8*)(&lb[col * 64 + ((q ^ (col & 7)) << 3)]);
          acc[g] = __builtin_amdgcn_mfma_f32_32x32x16_bf16(af, bfr, acc[g], 0, 0, 0);
        }
      }
    }

    // ---- epilogue half h: row t = edge, col = h*128 + g*32 + lm
#pragma unroll
    for (int g = 0; g < 4; ++g) {
      int col = h * 128 + (g << 5) + lm;
#pragma unroll
      for (int t = 0; t < 16; ++t) {
        if (er_ok[t]) {
          float v = acc[g][t] * nr[t];
          if (MODE == 0)
            __builtin_nontemporal_store(f2bf(v), &msg[(size_t)prow[t] * OUT_ + col]);
          else
            unsafeAtomicAdd(&acc_out[(size_t)db[t] + col], v);
        }
      }
    }
  }
}

// ---------------------------------------------------------------------------
// agg: msg rows are CSR-ordered -> perfectly streaming reads.
// One wave per node; lane owns 4 channels; fp32 register accumulation.
// ---------------------------------------------------------------------------
__launch_bounds__(256)
__global__ void agg_kernel(const short* __restrict__ msg, const int* __restrict__ offsets,
                           const int* __restrict__ counts, float* __restrict__ out) {
  int n = blockIdx.x * 4 + (threadIdx.x >> 6);
  if (n >= N_) return;
  int lane = threadIdx.x & 63;
  int off = offsets[n], cnt = counts[n];
  float4 a = make_float4(0.f, 0.f, 0.f, 0.f);
  const unsigned long long* __restrict__ m8 = (const unsigned long long*)msg; // row = 64 x 8B
  for (int j = 0; j < cnt; ++j) {
    unsigned long long v = __builtin_nontemporal_load(&m8[(size_t)(off + j) * 64 + lane]);
    a.x += bf2f((unsigned short)(v & 0xffffu));
    a.y += bf2f((unsigned short)((v >> 16) & 0xffffu));
    a.z += bf2f((unsigned short)((v >> 32) & 0xffffu));
    a.w += bf2f((unsigned short)(v >> 48));
  }
  ((float4*)out)[(size_t)n * 64 + lane] = a;
}

__global__ void zero_out_kernel(float* __restrict__ out) {
  int idx = blockIdx.x * 256 + threadIdx.x;
  if (idx < N_ * OUT_ / 4)
    ((float4*)out)[idx] = make_float4(0.f, 0.f, 0.f, 0.f);
}

// ---------------------------------------------------------------------------
// selfloop (EXACT r9/r1): out = relu(out + h_bias + feat @ loop_weight)
// ---------------------------------------------------------------------------
__launch_bounds__(256)
__global__ void selfloop_kernel(const short* __restrict__ feat_bf, const short* __restrict__ loopT,
                                const float* __restrict__ h_bias, float* __restrict__ inout) {
  __shared__ short lds_b[128 * 64];
  int bid = blockIdx.x;
  int mblk = bid >> 1, nhalf = bid & 1;
  int n0 = mblk << 7;
  int rows = N_ - n0; if (rows > 128) rows = 128;

  int tid = threadIdx.x;
  int lane = tid & 63, wave = tid >> 6;
  int lm = lane & 31, hi = lane >> 5;
  int wr = wave << 5;

  int nrow = wr + lm;
  int ng = n0 + (nrow < rows ? nrow : 0);
  const bf16x8* __restrict__ arow = (const bf16x8*)(feat_bf + (size_t)ng * IN_);
  const short*  __restrict__ wb   = loopT + nhalf * 128 * IN_;

  f32x16 acc[4];
#pragma unroll
  for (int g = 0; g < 4; ++g)
#pragma unroll
    for (int t = 0; t < 16; ++t) acc[g][t] = 0.f;

  int scol = tid >> 1, sh = tid & 1;
  const bf16x8* __restrict__ gsrc0 = (const bf16x8*)(wb + scol * IN_ + sh * 32);

  for (int stage = 0; stage < 4; ++stage) {
#pragma unroll
    for (int c8 = 0; c8 < 4; ++c8) {
      int q = sh * 4 + c8;
      bf16x8 v = gsrc0[stage * 8 + c8];
      *(bf16x8*)(&lds_b[scol * 64 + ((q ^ (scol & 7)) << 3)]) = v;
    }
    bf16x8 af[4];
#pragma unroll
    for (int s = 0; s < 4; ++s) af[s] = arow[stage * 8 + s * 2 + hi];
    __syncthreads();
#pragma unroll
    for (int s = 0; s < 4; ++s) {
      int q = s * 2 + hi;
#pragma unroll
      for (int g = 0; g < 4; ++g) {
        int col = (g << 5) + lm;
        bf16x8 bfr = *(const bf16x8*)(&lds_b[col * 64 + ((q ^ (col & 7)) << 3)]);
        acc[g] = __builtin_amdgcn_mfma_f32_32x32x16_bf16(af[s], bfr, acc[g], 0, 0, 0);
      }
    }
    __syncthreads();
  }

#pragma unroll
  for (int g = 0; g < 4; ++g) {
    int col = nhalf * 128 + (g << 5) + lm;
    float hb = h_bias[col];
#pragma unroll
    for (int t = 0; t < 16; ++t) {
      int row = (t & 3) + ((t >> 2) << 3) + (hi << 2);
      int nn = wr + row;
      if (nn < rows) {
        size_t off = (size_t)(n0 + nn) * OUT_ + col;
        float x = inout[off] + acc[g][t] + hb;
        inout[off] = x > 0.f ? x : 0.f;
      }
    }
  }
}

// ---------------------------------------------------------------------------
extern "C" void kernel_launch(void* const* d_in, const int* in_sizes, int n_in,
                              void* d_out, int out_size, void* d_ws, size_t ws_size,
                              hipStream_t stream) {
  const float* feat    = (const float*)d_in[0];
  const float* weight  = (const float*)d_in[1];
  const float* w_comp  = (const float*)d_in[2];
  const float* loop_w  = (const float*)d_in[3];
  const float* h_bias  = (const float*)d_in[4];
  const float* norm    = (const float*)d_in[5];
  const int*   src_idx = (const int*)d_in[6];
  const int*   dst_idx = (const int*)d_in[7];
  float* out = (float*)d_out;

  short* w_relT  = (short*)d_ws;                 // 2 MB
  short* w_relS  = w_relT + R_ * OUT_ * IN_;     // 2 MB (pre-swizzled LDS image)
  short* loopT   = w_relS + R_ * OUT_ * IN_;     // 128 KB
  short* feat_bf = loopT + OUT_ * IN_;           // 25.6 MB
  int*   counts  = (int*)(feat_bf + (size_t)N_ * IN_);  // 200 KB
  int*   offsets = counts + N_;                  // 200 KB
  int*   woff    = offsets + N_;                 // 200 KB
  int*   bsum    = woff + N_;                    // 1 KB (scan block sums)
  int*   pos     = bsum + 256;                   // 1.28 MB (edge -> CSR slot)
  short* msg     = (short*)(pos + E_);           // 163.84 MB (bf16, CSR-ordered)
  size_t need    = (size_t)((char*)(msg + (size_t)E_ * OUT_) - (char*)d_ws);

  prep_kernel<<<1024, 256, 0, stream>>>(feat, weight, w_comp, loop_w,
                                        w_relT, loopT, feat_bf, counts);
  reorder_kernel<<<(R_ * OUT_ * IN_) / 256, 256, 0, stream>>>(w_relT, w_relS);

  if (ws_size >= need) {
    // CSR path: permuted bf16 msg (nt stores), streaming aggregation
    hist_kernel<<<(E_ + 255) / 256, 256, 0, stream>>>(dst_idx, counts);
    scan1_kernel<<<SBLK_, 256, 0, stream>>>(counts, offsets, bsum);
    scan2_kernel<<<1, 256, 0, stream>>>(bsum);
    scan3_kernel<<<SBLK_, 256, 0, stream>>>(offsets, bsum, woff);
    scatter_kernel<<<(E_ + 255) / 256, 256, 0, stream>>>(dst_idx, woff, pos);
    edge_kernel<0><<<MBLK_ * R_, 256, 0, stream>>>(feat_bf, w_relS, norm, src_idx, dst_idx,
                                                   pos, msg, nullptr);
    agg_kernel<<<(N_ + 3) / 4, 256, 0, stream>>>(msg, offsets, counts, out);
  } else {
    // fallback: fp32 atomic scatter
    zero_out_kernel<<<(N_ * OUT_ / 4 + 255) / 256, 256, 0, stream>>>(out);
    edge_kernel<1><<<MBLK_ * R_, 256, 0, stream>>>(feat_bf, w_relS, norm, src_idx, dst_idx,
                                                   nullptr, nullptr, out);
  }

  selfloop_kernel<<<NBLK_ * 2, 256, 0, stream>>>(feat_bf, loopT, h_bias, out);
}